// Round 1
// baseline (980.150 us; speedup 1.0000x reference)
//
#include <hip/hip_runtime.h>
#include <stdint.h>

#define B_ 8
#define T_ 288
#define N_ 307
#define E_ 4912
#define NTH 1024  // 16 waves, single workgroup for the whole GAT

static __device__ __forceinline__ int rfl(int x) { return __builtin_amdgcn_readfirstlane(x); }

struct GatLds {
    float ss[N_ * 8];     // source attention coeff per (node, head)
    float st[N_ * 8];     // target attention coeff per (node, head)
    float den[N_ * 8];    // softmax denominator per (node, head)
    int   csrc[E_];       // src node id, sorted by tgt (CSR payload)
    int   ofs[N_ + 1];    // CSR row offsets by tgt
    int   cnt[512];       // degree counters / scan workspace / fill cursors
};
// total ~52.4 KB LDS — fits static 64 KB

// One GAT layer. hin -> hnext. p/ev staged in global (L2-resident).
template <int H, int F, bool IDENT, bool LAST>
static __device__ __forceinline__ void gat_layer(
    const float* __restrict__ hin, float* __restrict__ hnext,
    const float* __restrict__ Wg, const float* __restrict__ skipWg,
    const float* __restrict__ asg, const float* __restrict__ atg,
    const float* __restrict__ bg,
    float* __restrict__ pbuf, float* __restrict__ evbuf,
    GatLds& L, int tid, int wid, int lane)
{
    const int h = lane / F;  // F=8 -> lane>>3 ; F=64 -> 0

    // ---- projection p = hin @ W, plus ss/st via in-wave reduction ----
    {
        float wc[64];
#pragma unroll
        for (int k = 0; k < 64; k++) wc[k] = Wg[k * 64 + lane];  // coalesced, once per layer
        const float as = asg[lane], at = atg[lane];
        for (int n = wid; n < N_; n += 16) {  // n is wave-uniform
            const float* hr = hin + n * 64;
            float a0 = 0.f, a1 = 0.f, a2 = 0.f, a3 = 0.f;
#pragma unroll
            for (int k = 0; k < 64; k += 4) {
                a0 += hr[k + 0] * wc[k + 0];
                a1 += hr[k + 1] * wc[k + 1];
                a2 += hr[k + 2] * wc[k + 2];
                a3 += hr[k + 3] * wc[k + 3];
            }
            float pd = (a0 + a1) + (a2 + a3);
            pbuf[n * 64 + lane] = pd;
            // ss/st: reduce p*a over the F lanes of each head
            float c0 = pd * as, c1 = pd * at;
#pragma unroll
            for (int o = 1; o < F; o <<= 1) {
                c0 += __shfl_xor(c0, o, 64);
                c1 += __shfl_xor(c1, o, 64);
            }
            if ((lane & (F - 1)) == 0) {
                L.ss[n * H + h] = c0;
                L.st[n * H + h] = c1;
            }
        }
    }

    // ---- projected skip init: hnext = hin @ skipW (layers 0,1) ----
    if (!IDENT) {
        float wc[64];
#pragma unroll
        for (int k = 0; k < 64; k++) wc[k] = skipWg[k * 64 + lane];
        for (int n = wid; n < N_; n += 16) {
            const float* hr = hin + n * 64;
            float a0 = 0.f, a1 = 0.f, a2 = 0.f, a3 = 0.f;
#pragma unroll
            for (int k = 0; k < 64; k += 4) {
                a0 += hr[k + 0] * wc[k + 0];
                a1 += hr[k + 1] * wc[k + 1];
                a2 += hr[k + 2] * wc[k + 2];
                a3 += hr[k + 3] * wc[k + 3];
            }
            hnext[n * 64 + lane] = (a0 + a1) + (a2 + a3);
        }
    }
    __syncthreads();  // p, ss, st, skip ready

    // ---- edge scores: one owner thread per (node, head); exact max, no atomics ----
    for (int i = tid; i < N_ * H; i += NTH) {
        const int n = i / H, hh = i % H;
        const float sth = L.st[i];
        const int e0 = L.ofs[n], e1 = L.ofs[n + 1];
        float m = -1e30f;
        for (int e = e0; e < e1; e++) {
            float s = L.ss[L.csrc[e] * H + hh] + sth;
            s = s > 0.f ? s : 0.2f * s;  // leaky_relu(0.2)
            m = fmaxf(m, s);
        }
        float dsum = 0.f;
        for (int e = e0; e < e1; e++) {
            float s = L.ss[L.csrc[e] * H + hh] + sth;
            s = s > 0.f ? s : 0.2f * s;
            float ev = expf(s - m);
            dsum += ev;
            evbuf[e * H + hh] = ev;  // indexed by CSR position
        }
        L.den[i] = dsum;
    }
    __syncthreads();  // ev, den ready

    // ---- aggregation + finalize: one wave per node ----
    const float bb = bg[lane];
    for (int n = wid; n < N_; n += 16) {
        const int e0 = L.ofs[n], e1 = L.ofs[n + 1];
        float num = 0.f;
        for (int e = e0; e < e1; e++) {
            const int s = L.csrc[e];
            num += evbuf[e * H + h] * pbuf[s * 64 + lane];  // coalesced 256B p-row gather (L2)
        }
        const float dsum = L.den[n * H + h];
        const float out = num / (dsum + 1e-16f);
        const float sk = IDENT ? hin[n * 64 + lane] : hnext[n * 64 + lane];
        float v = out + sk + bb;
        if (!LAST) v = v > 0.f ? v : expm1f(v);  // elu
        hnext[n * 64 + lane] = v;
    }
    __syncthreads();  // hnext complete before next layer reuses ss/st/den/pbuf
}

// ---------- single-block kernel: PE table + h0 + CSR + 3 GAT layers ----------
__global__ __launch_bounds__(NTH, 1) void k_gat(
    const float* __restrict__ b_val,
    const float* __restrict__ nfeat, const float* __restrict__ W_sta,
    const float* __restrict__ b_sta, const float* __restrict__ ada,
    const int* __restrict__ src, const int* __restrict__ tgt,
    const float* __restrict__ g0W, const float* __restrict__ g0as,
    const float* __restrict__ g0at, const float* __restrict__ g0b,
    const float* __restrict__ g0skip,
    const float* __restrict__ g1W, const float* __restrict__ g1as,
    const float* __restrict__ g1at, const float* __restrict__ g1b,
    const float* __restrict__ g1skip,
    const float* __restrict__ g2W, const float* __restrict__ g2as,
    const float* __restrict__ g2at, const float* __restrict__ g2b,
    float* __restrict__ Q, float* __restrict__ h0, float* __restrict__ h1,
    float* __restrict__ h2, float* __restrict__ h3,
    float* __restrict__ pbuf, float* __restrict__ evbuf)
{
    __shared__ GatLds L;
    const int tid = threadIdx.x;
    const int lane = tid & 63;
    const int wid = rfl(tid >> 6);  // wave id 0..15, forced uniform

    // ---- Q[t,d] = pe(t,d) + b_val[d] (same formulas as reference) ----
    for (int i = tid; i < T_ * 64; i += NTH) {
        int t = i >> 6, d = i & 63;
        float div = expf(-(float)(d & ~1) * (9.210340371976184f / 64.0f));  // ln(1e4)/64
        float ang = (float)t * div;
        Q[i] = ((d & 1) ? cosf(ang) : sinf(ang)) + b_val[d];
    }

    // ---- CSR build by tgt (counting sort, once for all 3 layers) ----
    for (int i = tid; i < 512; i += NTH) L.cnt[i] = 0;
    __syncthreads();
    for (int e = tid; e < E_; e += NTH) atomicAdd(&L.cnt[tgt[e]], 1);
    __syncthreads();
    // Hillis-Steele inclusive scan over 512 (zero-padded past N_)
    for (int o = 1; o < 512; o <<= 1) {
        int v = 0;
        if (tid < 512 && tid >= o) v = L.cnt[tid - o];
        __syncthreads();
        if (tid < 512) L.cnt[tid] += v;
        __syncthreads();
    }
    if (tid <= N_) L.ofs[tid] = (tid == 0) ? 0 : L.cnt[tid - 1];
    __syncthreads();
    for (int i = tid; i < 512; i += NTH) L.cnt[i] = 0;
    __syncthreads();
    for (int e = tid; e < E_; e += NTH) {
        int t = tgt[e];
        int pos = L.ofs[t] + atomicAdd(&L.cnt[t], 1);
        L.csrc[pos] = src[e];
    }

    // ---- h0 = nfeat @ W_sta + b_sta + ada ----
    {
        float wc[32];
#pragma unroll
        for (int k = 0; k < 32; k++) wc[k] = W_sta[k * 64 + lane];
        const float bs = b_sta[lane];
        for (int n = wid; n < N_; n += 16) {
            const float* nr = nfeat + n * 32;  // wave-uniform row
            float a = bs + ada[n * 64 + lane];
#pragma unroll
            for (int k = 0; k < 32; k++) a += nr[k] * wc[k];
            h0[n * 64 + lane] = a;
        }
    }
    __syncthreads();  // h0 + CSR ready

    gat_layer<8, 8, false, false>(h0, h1, g0W, g0skip, g0as, g0at, g0b, pbuf, evbuf, L, tid, wid, lane);
    gat_layer<8, 8, false, false>(h1, h2, g1W, g1skip, g1as, g1at, g1b, pbuf, evbuf, L, tid, wid, lane);
    gat_layer<1, 64, true, true>(h2, h3, g2W, nullptr, g2as, g2at, g2b, pbuf, evbuf, L, tid, wid, lane);
}

// ---------- broadcast: out[b,t,n,d] = x*Wv[d] + Q[t,d] + h3[n,d] ----------
__global__ __launch_bounds__(256) void k_big(const float* __restrict__ x,
                                             const float* __restrict__ Q,
                                             const float* __restrict__ Wv,
                                             const float* __restrict__ h3,
                                             float* __restrict__ out) {
    int row = blockIdx.x * 32 + (threadIdx.x >> 3);  // (b,t,n) linear
    int l8 = threadIdx.x & 7;
    int d0 = l8 * 8;
    int n = row % N_;
    int bt = row / N_;
    int t = bt % T_;
    float xv = x[row];
    float4 q0 = *(const float4*)(Q + t * 64 + d0);
    float4 q1 = *(const float4*)(Q + t * 64 + d0 + 4);
    float4 g0 = *(const float4*)(h3 + n * 64 + d0);
    float4 g1 = *(const float4*)(h3 + n * 64 + d0 + 4);
    float4 w0 = *(const float4*)(Wv + d0);
    float4 w1 = *(const float4*)(Wv + d0 + 4);
    float4 o0, o1;
    o0.x = fmaf(xv, w0.x, q0.x + g0.x);
    o0.y = fmaf(xv, w0.y, q0.y + g0.y);
    o0.z = fmaf(xv, w0.z, q0.z + g0.z);
    o0.w = fmaf(xv, w0.w, q0.w + g0.w);
    o1.x = fmaf(xv, w1.x, q1.x + g1.x);
    o1.y = fmaf(xv, w1.y, q1.y + g1.y);
    o1.z = fmaf(xv, w1.z, q1.z + g1.z);
    o1.w = fmaf(xv, w1.w, q1.w + g1.w);
    float* op = out + row * 64 + d0;
    *(float4*)(op) = o0;
    *(float4*)(op + 4) = o1;
}

extern "C" void kernel_launch(void* const* d_in, const int* in_sizes, int n_in,
                              void* d_out, int out_size, void* d_ws, size_t ws_size,
                              hipStream_t stream) {
    const float* x      = (const float*)d_in[0];
    const float* nfeat  = (const float*)d_in[1];
    const int*   eidx   = (const int*)d_in[2];
    // d_in[3] edge_prob unused (load_trans_prob=False)
    const float* W_val  = (const float*)d_in[4];
    const float* b_val  = (const float*)d_in[5];
    const float* W_sta  = (const float*)d_in[6];
    const float* b_sta  = (const float*)d_in[7];
    const float* ada    = (const float*)d_in[8];
    const float* g0W    = (const float*)d_in[9];
    const float* g0as   = (const float*)d_in[10];
    const float* g0at   = (const float*)d_in[11];
    const float* g0b    = (const float*)d_in[12];
    const float* g1W    = (const float*)d_in[13];
    const float* g1as   = (const float*)d_in[14];
    const float* g1at   = (const float*)d_in[15];
    const float* g1b    = (const float*)d_in[16];
    const float* g2W    = (const float*)d_in[17];
    const float* g2as   = (const float*)d_in[18];
    const float* g2at   = (const float*)d_in[19];
    const float* g2b    = (const float*)d_in[20];
    const float* g0skip = (const float*)d_in[21];
    const float* g1skip = (const float*)d_in[22];
    (void)in_sizes; (void)n_in; (void)out_size; (void)ws_size;

    const int* src = eidx;
    const int* tgt = eidx + E_;

    // workspace layout (fp32), ~624 KB
    float* ws    = (float*)d_ws;
    float* Q     = ws;               // 288*64
    float* h0    = Q + T_ * 64;      // 307*64 each
    float* h1    = h0 + N_ * 64;
    float* h2    = h1 + N_ * 64;
    float* h3    = h2 + N_ * 64;
    float* pbuf  = h3 + N_ * 64;
    float* evbuf = pbuf + N_ * 64;   // 4912*8

    // entire GAT (tables + CSR + 3 layers) in one single-CU dispatch
    k_gat<<<1, NTH, 0, stream>>>(b_val, nfeat, W_sta, b_sta, ada, src, tgt,
                                 g0W, g0as, g0at, g0b, g0skip,
                                 g1W, g1as, g1at, g1b, g1skip,
                                 g2W, g2as, g2at, g2b,
                                 Q, h0, h1, h2, h3, pbuf, evbuf);

    // broadcast: 707328 rows, 32 rows/block (HBM-write roofline)
    const int ROWS = B_ * T_ * N_;  // 707328
    k_big<<<ROWS / 32, 256, 0, stream>>>(x, Q, W_val, h3, (float*)d_out);
}

// Round 2
// 776.356 us; speedup vs baseline: 1.2625x; 1.2625x over previous
//
#include <hip/hip_runtime.h>
#include <stdint.h>

#define B_ 8
#define T_ 288
#define N_ 307
#define E_ 4912
#define NTH 1024  // 16 waves, single workgroup for the whole GAT

static __device__ __forceinline__ int rfl(int x) { return __builtin_amdgcn_readfirstlane(x); }

// All hot GAT state lives in LDS (121,168 B of the CU's 160 KiB).
struct GatLds {
    float pbuf[N_ * 64];  // projected features p            78,592 B
    float ss[N_ * 8];     // src attention coeff (node,head)  9,824 B
    float st[N_ * 8];     // tgt attention coeff (node,head)  9,824 B
    int   csrc[E_];       // src ids sorted by tgt (CSR)     19,648 B
    int   ofs[N_ + 1];    // CSR row offsets                  1,232 B
    int   cnt[512];       // degree / scan / cursor scratch   2,048 B
};

// One GAT layer, fully in-LDS. hin/hnext are small global (L2) buffers.
template <int H, int F, bool IDENT, bool LAST>
static __device__ __forceinline__ void gat_layer(
    const float* __restrict__ hin, float* __restrict__ hnext,
    const float* __restrict__ Wg, const float* __restrict__ skipWg,
    const float* __restrict__ asg, const float* __restrict__ atg,
    const float* __restrict__ bg,
    GatLds& L, int tid, int wid, int lane)
{
    const int h = lane / F;        // head of this lane (F=8 -> lane>>3 ; F=64 -> 0)
    const int f = lane & (F - 1);  // position within head group

    // ---- phase 1a: p = hin @ W -> LDS; ss/st via in-wave reduction -> LDS ----
    {
        float wc[64];
#pragma unroll
        for (int k = 0; k < 64; k++) wc[k] = Wg[k * 64 + lane];  // coalesced, once per layer
        const float as = asg[lane], at = atg[lane];
        for (int n = wid; n < N_; n += 16) {  // n wave-uniform
            const float4* hr = (const float4*)(hin + n * 64);
            float a0 = 0.f, a1 = 0.f, a2 = 0.f, a3 = 0.f;
#pragma unroll
            for (int q = 0; q < 16; q++) {  // wave-uniform float4 loads, independent -> pipelined
                float4 hv = hr[q];
                a0 = fmaf(hv.x, wc[4 * q + 0], a0);
                a1 = fmaf(hv.y, wc[4 * q + 1], a1);
                a2 = fmaf(hv.z, wc[4 * q + 2], a2);
                a3 = fmaf(hv.w, wc[4 * q + 3], a3);
            }
            float pd = (a0 + a1) + (a2 + a3);
            L.pbuf[n * 64 + lane] = pd;  // lane-consecutive: conflict-free
            float c0 = pd * as, c1 = pd * at;
#pragma unroll
            for (int o = 1; o < F; o <<= 1) {  // reduce over the F lanes of each head
                c0 += __shfl_xor(c0, o, 64);
                c1 += __shfl_xor(c1, o, 64);
            }
            if (f == 0) { L.ss[n * H + h] = c0; L.st[n * H + h] = c1; }
        }
    }

    // ---- phase 1b: projected skip hnext = hin @ skipW (layers 0,1) ----
    if (!IDENT) {
        float wc[64];
#pragma unroll
        for (int k = 0; k < 64; k++) wc[k] = skipWg[k * 64 + lane];
        for (int n = wid; n < N_; n += 16) {
            const float4* hr = (const float4*)(hin + n * 64);
            float a0 = 0.f, a1 = 0.f, a2 = 0.f, a3 = 0.f;
#pragma unroll
            for (int q = 0; q < 16; q++) {
                float4 hv = hr[q];
                a0 = fmaf(hv.x, wc[4 * q + 0], a0);
                a1 = fmaf(hv.y, wc[4 * q + 1], a1);
                a2 = fmaf(hv.z, wc[4 * q + 2], a2);
                a3 = fmaf(hv.w, wc[4 * q + 3], a3);
            }
            hnext[n * 64 + lane] = (a0 + a1) + (a2 + a3);
        }
    }
    __syncthreads();  // p, ss, st complete for ALL nodes (edges reference any src)

    // ---- phase 2: per-node softmax + aggregate + finalize, one wave per node ----
    // exact max: strided pass within head group, shfl_xor reduce; then a single
    // full pass recomputing exp inline (no ev buffer, no atomics, all LDS).
    const float bb = bg[lane];
    for (int n = wid; n < N_; n += 16) {
        const int e0 = L.ofs[n], e1 = L.ofs[n + 1];
        const float sth = L.st[n * H + h];
        float m = -1e30f;
        for (int e = e0 + f; e < e1; e += F) {
            float s = L.ss[L.csrc[e] * H + h] + sth;
            s = s > 0.f ? s : 0.2f * s;  // leaky_relu(0.2)
            m = fmaxf(m, s);
        }
#pragma unroll
        for (int o = 1; o < F; o <<= 1) m = fmaxf(m, __shfl_xor(m, o, 64));
        float num = 0.f, den = 0.f;
        for (int e = e0; e < e1; e++) {  // e wave-uniform: csrc broadcast read
            const int s = L.csrc[e];
            float sc = L.ss[s * H + h] + sth;      // <=8 distinct words: broadcast
            sc = sc > 0.f ? sc : 0.2f * sc;
            float ev = __expf(sc - m);             // v_exp_f32
            den += ev;                             // same ev across head group -> den exact
            num = fmaf(ev, L.pbuf[s * 64 + lane], num);  // 2-way-aliased row read: free
        }
        float out = num / (den + 1e-16f);
        float sk = IDENT ? hin[n * 64 + lane] : hnext[n * 64 + lane];
        float v = out + sk + bb;
        if (!LAST) v = v > 0.f ? v : expm1f(v);  // elu
        hnext[n * 64 + lane] = v;
    }
    __syncthreads();  // hnext done before next layer reuses pbuf/ss/st
}

// ---------- single-block kernel: PE table + CSR + h0 + 3 GAT layers ----------
__global__ __launch_bounds__(NTH, 4) void k_gat(
    const float* __restrict__ b_val,
    const float* __restrict__ nfeat, const float* __restrict__ W_sta,
    const float* __restrict__ b_sta, const float* __restrict__ ada,
    const int* __restrict__ src, const int* __restrict__ tgt,
    const float* __restrict__ g0W, const float* __restrict__ g0as,
    const float* __restrict__ g0at, const float* __restrict__ g0b,
    const float* __restrict__ g0skip,
    const float* __restrict__ g1W, const float* __restrict__ g1as,
    const float* __restrict__ g1at, const float* __restrict__ g1b,
    const float* __restrict__ g1skip,
    const float* __restrict__ g2W, const float* __restrict__ g2as,
    const float* __restrict__ g2at, const float* __restrict__ g2b,
    float* __restrict__ Q, float* __restrict__ h0, float* __restrict__ h1,
    float* __restrict__ h2, float* __restrict__ h3)
{
    __shared__ GatLds L;
    const int tid = threadIdx.x;
    const int lane = tid & 63;
    const int wid = rfl(tid >> 6);  // wave id 0..15, forced uniform

    // ---- Q[t,d] = pe(t,d) + b_val[d] ----
    for (int i = tid; i < T_ * 64; i += NTH) {
        int t = i >> 6, d = i & 63;
        float div = expf(-(float)(d & ~1) * (9.210340371976184f / 64.0f));  // ln(1e4)/64
        float ang = (float)t * div;
        Q[i] = ((d & 1) ? cosf(ang) : sinf(ang)) + b_val[d];
    }

    // ---- CSR build by tgt (counting sort in LDS, once for all 3 layers) ----
    for (int i = tid; i < 512; i += NTH) L.cnt[i] = 0;
    __syncthreads();
    for (int e = tid; e < E_; e += NTH) atomicAdd(&L.cnt[tgt[e]], 1);
    __syncthreads();
    for (int o = 1; o < 512; o <<= 1) {  // Hillis-Steele inclusive scan
        int v = 0;
        if (tid < 512 && tid >= o) v = L.cnt[tid - o];
        __syncthreads();
        if (tid < 512) L.cnt[tid] += v;
        __syncthreads();
    }
    if (tid <= N_) L.ofs[tid] = (tid == 0) ? 0 : L.cnt[tid - 1];
    __syncthreads();
    for (int i = tid; i < 512; i += NTH) L.cnt[i] = 0;
    __syncthreads();
    for (int e = tid; e < E_; e += NTH) {
        int t = tgt[e];
        int pos = L.ofs[t] + atomicAdd(&L.cnt[t], 1);
        L.csrc[pos] = src[e];
    }

    // ---- h0 = nfeat @ W_sta + b_sta + ada ----
    {
        float wc[32];
#pragma unroll
        for (int k = 0; k < 32; k++) wc[k] = W_sta[k * 64 + lane];
        const float bs = b_sta[lane];
        for (int n = wid; n < N_; n += 16) {
            const float4* nr = (const float4*)(nfeat + n * 32);
            float a = bs + ada[n * 64 + lane];
#pragma unroll
            for (int q = 0; q < 8; q++) {
                float4 nv = nr[q];
                a = fmaf(nv.x, wc[4 * q + 0], a);
                a = fmaf(nv.y, wc[4 * q + 1], a);
                a = fmaf(nv.z, wc[4 * q + 2], a);
                a = fmaf(nv.w, wc[4 * q + 3], a);
            }
            h0[n * 64 + lane] = a;
        }
    }
    __syncthreads();  // h0 + CSR ready

    gat_layer<8, 8, false, false>(h0, h1, g0W, g0skip, g0as, g0at, g0b, L, tid, wid, lane);
    gat_layer<8, 8, false, false>(h1, h2, g1W, g1skip, g1as, g1at, g1b, L, tid, wid, lane);
    gat_layer<1, 64, true, true>(h2, h3, g2W, nullptr, g2as, g2at, g2b, L, tid, wid, lane);
}

// ---------- broadcast: out[b,t,n,d] = x*Wv[d] + Q[t,d] + h3[n,d] ----------
__global__ __launch_bounds__(256) void k_big(const float* __restrict__ x,
                                             const float* __restrict__ Q,
                                             const float* __restrict__ Wv,
                                             const float* __restrict__ h3,
                                             float* __restrict__ out) {
    int row = blockIdx.x * 32 + (threadIdx.x >> 3);  // (b,t,n) linear
    int l8 = threadIdx.x & 7;
    int d0 = l8 * 8;
    int n = row % N_;
    int bt = row / N_;
    int t = bt % T_;
    float xv = x[row];
    float4 q0 = *(const float4*)(Q + t * 64 + d0);
    float4 q1 = *(const float4*)(Q + t * 64 + d0 + 4);
    float4 g0 = *(const float4*)(h3 + n * 64 + d0);
    float4 g1 = *(const float4*)(h3 + n * 64 + d0 + 4);
    float4 w0 = *(const float4*)(Wv + d0);
    float4 w1 = *(const float4*)(Wv + d0 + 4);
    float4 o0, o1;
    o0.x = fmaf(xv, w0.x, q0.x + g0.x);
    o0.y = fmaf(xv, w0.y, q0.y + g0.y);
    o0.z = fmaf(xv, w0.z, q0.z + g0.z);
    o0.w = fmaf(xv, w0.w, q0.w + g0.w);
    o1.x = fmaf(xv, w1.x, q1.x + g1.x);
    o1.y = fmaf(xv, w1.y, q1.y + g1.y);
    o1.z = fmaf(xv, w1.z, q1.z + g1.z);
    o1.w = fmaf(xv, w1.w, q1.w + g1.w);
    float* op = out + row * 64 + d0;
    *(float4*)(op) = o0;
    *(float4*)(op + 4) = o1;
}

extern "C" void kernel_launch(void* const* d_in, const int* in_sizes, int n_in,
                              void* d_out, int out_size, void* d_ws, size_t ws_size,
                              hipStream_t stream) {
    const float* x      = (const float*)d_in[0];
    const float* nfeat  = (const float*)d_in[1];
    const int*   eidx   = (const int*)d_in[2];
    // d_in[3] edge_prob unused (load_trans_prob=False)
    const float* W_val  = (const float*)d_in[4];
    const float* b_val  = (const float*)d_in[5];
    const float* W_sta  = (const float*)d_in[6];
    const float* b_sta  = (const float*)d_in[7];
    const float* ada    = (const float*)d_in[8];
    const float* g0W    = (const float*)d_in[9];
    const float* g0as   = (const float*)d_in[10];
    const float* g0at   = (const float*)d_in[11];
    const float* g0b    = (const float*)d_in[12];
    const float* g1W    = (const float*)d_in[13];
    const float* g1as   = (const float*)d_in[14];
    const float* g1at   = (const float*)d_in[15];
    const float* g1b    = (const float*)d_in[16];
    const float* g2W    = (const float*)d_in[17];
    const float* g2as   = (const float*)d_in[18];
    const float* g2at   = (const float*)d_in[19];
    const float* g2b    = (const float*)d_in[20];
    const float* g0skip = (const float*)d_in[21];
    const float* g1skip = (const float*)d_in[22];
    (void)in_sizes; (void)n_in; (void)out_size; (void)ws_size;

    const int* src = eidx;
    const int* tgt = eidx + E_;

    // workspace layout (fp32), ~152 KB
    float* ws = (float*)d_ws;
    float* Q  = ws;              // 288*64
    float* h0 = Q + T_ * 64;     // 307*64 each
    float* h1 = h0 + N_ * 64;
    float* h2 = h1 + N_ * 64;
    float* h3 = h2 + N_ * 64;

    // entire GAT (tables + CSR + 3 layers) in one single-CU, LDS-resident dispatch
    k_gat<<<1, NTH, 0, stream>>>(b_val, nfeat, W_sta, b_sta, ada, src, tgt,
                                 g0W, g0as, g0at, g0b, g0skip,
                                 g1W, g1as, g1at, g1b, g1skip,
                                 g2W, g2as, g2at, g2b,
                                 Q, h0, h1, h2, h3);

    // broadcast: 707328 rows, 32 rows/block (HBM-write roofline)
    const int ROWS = B_ * T_ * N_;  // 707328
    k_big<<<ROWS / 32, 256, 0, stream>>>(x, Q, W_val, h3, (float*)d_out);
}

// Round 3
// 409.216 us; speedup vs baseline: 2.3952x; 1.8972x over previous
//
#include <hip/hip_runtime.h>
#include <hip/hip_cooperative_groups.h>
#include <stdint.h>

namespace cg = cooperative_groups;

#define B_ 8
#define T_ 288
#define N_ 307
#define E_ 4912
#define NWG 32            // cooperative workgroups (CUs used)
#define WGS 256           // threads per WG (4 waves)
#define GW  (NWG * WGS / 64)  // 128 waves total

static __device__ __forceinline__ int rfl(int x) { return __builtin_amdgcn_readfirstlane(x); }

struct Params {
    const float* nfeat; const int* src; const int* tgt;
    const float* b_val; const float* W_sta; const float* b_sta; const float* ada;
    const float* g0W; const float* g0as; const float* g0at; const float* g0b; const float* g0skip;
    const float* g1W; const float* g1as; const float* g1at; const float* g1b; const float* g1skip;
    const float* g2W; const float* g2as; const float* g2at; const float* g2b;
    float* Q; float* h0; float* h1; float* h2; float* h3;
    float* pbuf; float* ss; float* st; int* csrc; int* ofs;
};

// One GAT layer across the whole grid. All shared state in global (L2/LLC).
template <int H, int F, bool IDENT, bool LAST>
static __device__ __forceinline__ void gat_layer(
    const float* __restrict__ hin, float* __restrict__ hnext,
    const float* __restrict__ Wg, const float* __restrict__ skipWg,
    const float* __restrict__ asg, const float* __restrict__ atg,
    const float* __restrict__ bg,
    float* __restrict__ pbuf, float* __restrict__ ss, float* __restrict__ st,
    const int* __restrict__ csrc, const int* __restrict__ ofs,
    cg::grid_group& grid, int gwid, int lane)
{
    const int h = lane / F;        // head (F=8 -> lane>>3 ; F=64 -> 0)
    const int f = lane & (F - 1);  // pos within head group

    // ---- proj: p = hin @ W -> pbuf ; ss/st via in-wave reduction ----
    {
        float wc[64];
#pragma unroll
        for (int k = 0; k < 64; k++) wc[k] = Wg[k * 64 + lane];  // stays in VGPRs (256 budget)
        const float as = asg[lane], at = atg[lane];
        for (int n = gwid; n < N_; n += GW) {  // ~2.4 nodes per wave
            const float4* hr = (const float4*)(hin + n * 64);
            float a0 = 0.f, a1 = 0.f, a2 = 0.f, a3 = 0.f;
#pragma unroll
            for (int q = 0; q < 16; q++) {
                float4 hv = hr[q];
                a0 = fmaf(hv.x, wc[4 * q + 0], a0);
                a1 = fmaf(hv.y, wc[4 * q + 1], a1);
                a2 = fmaf(hv.z, wc[4 * q + 2], a2);
                a3 = fmaf(hv.w, wc[4 * q + 3], a3);
            }
            float pd = (a0 + a1) + (a2 + a3);
            pbuf[n * 64 + lane] = pd;
            float c0 = pd * as, c1 = pd * at;
#pragma unroll
            for (int o = 1; o < F; o <<= 1) {
                c0 += __shfl_xor(c0, o, 64);
                c1 += __shfl_xor(c1, o, 64);
            }
            if (f == 0) { ss[n * H + h] = c0; st[n * H + h] = c1; }
        }
    }
    // ---- projected skip (layers 0,1): hnext = hin @ skipW ----
    if (!IDENT) {
        float wc[64];
#pragma unroll
        for (int k = 0; k < 64; k++) wc[k] = skipWg[k * 64 + lane];
        for (int n = gwid; n < N_; n += GW) {
            const float4* hr = (const float4*)(hin + n * 64);
            float a0 = 0.f, a1 = 0.f, a2 = 0.f, a3 = 0.f;
#pragma unroll
            for (int q = 0; q < 16; q++) {
                float4 hv = hr[q];
                a0 = fmaf(hv.x, wc[4 * q + 0], a0);
                a1 = fmaf(hv.y, wc[4 * q + 1], a1);
                a2 = fmaf(hv.z, wc[4 * q + 2], a2);
                a3 = fmaf(hv.w, wc[4 * q + 3], a3);
            }
            hnext[n * 64 + lane] = (a0 + a1) + (a2 + a3);
        }
    }
    grid.sync();  // p, ss, st, skip visible grid-wide

    // ---- softmax + aggregate + finalize: one wave per node ----
    const float bb = bg[lane];
    for (int n = gwid; n < N_; n += GW) {
        const int e0 = ofs[n], e1 = ofs[n + 1];
        const float sth = st[n * H + h];
        float m = -1e30f;
        for (int e = e0 + f; e < e1; e += F) {  // strided exact-max pass
            float s = ss[csrc[e] * H + h] + sth;
            s = s > 0.f ? s : 0.2f * s;  // leaky_relu(0.2)
            m = fmaxf(m, s);
        }
#pragma unroll
        for (int o = 1; o < F; o <<= 1) m = fmaxf(m, __shfl_xor(m, o, 64));
        float num = 0.f, den = 0.f;
        for (int e = e0; e < e1; e++) {  // e wave-uniform
            const int s = csrc[e];
            float sc = ss[s * H + h] + sth;
            sc = sc > 0.f ? sc : 0.2f * sc;
            float ev = __expf(sc - m);
            den += ev;
            num = fmaf(ev, pbuf[s * 64 + lane], num);  // coalesced 256B row gather
        }
        float outv = num / (den + 1e-16f);
        float sk = IDENT ? hin[n * 64 + lane] : hnext[n * 64 + lane];
        float v = outv + sk + bb;
        if (!LAST) v = v > 0.f ? v : expm1f(v);  // elu
        hnext[n * 64 + lane] = v;
    }
    grid.sync();  // hnext done before pbuf/ss/st reuse
}

// ---------- cooperative kernel: PE + h0 + CSR (parallel) then 3 GAT layers ----------
__global__ __launch_bounds__(WGS, 2) void k_gat(Params P) {
    cg::grid_group grid = cg::this_grid();
    const int tid = threadIdx.x;
    const int lane = tid & 63;
    const int gwid = rfl((int)(blockIdx.x * (WGS / 64) + (tid >> 6)));  // 0..127

    if (blockIdx.x == 0) {
        // ---- WG0: build CSR (sorted by tgt) in LDS, publish to global ----
        __shared__ int sA[512], sB[512], scur[512];
        for (int i = tid; i < 512; i += WGS) sA[i] = 0;
        __syncthreads();
        for (int e = tid; e < E_; e += WGS) atomicAdd(&sA[P.tgt[e]], 1);
        __syncthreads();
        int* in = sA; int* out = sB;
        for (int o = 1; o < 512; o <<= 1) {  // Hillis-Steele inclusive scan
            for (int i = tid; i < 512; i += WGS) {
                int v = in[i];
                if (i >= o) v += in[i - o];
                out[i] = v;
            }
            __syncthreads();
            int* t = in; in = out; out = t;
        }
        for (int i = tid; i <= N_; i += WGS) P.ofs[i] = (i == 0) ? 0 : in[i - 1];
        for (int i = tid; i < 512; i += WGS) scur[i] = 0;
        __syncthreads();
        for (int e = tid; e < E_; e += WGS) {
            int t = P.tgt[e];
            int base = (t == 0) ? 0 : in[t - 1];
            int pos = base + atomicAdd(&scur[t], 1);
            P.csrc[pos] = P.src[e];
        }
    } else {
        // ---- WGs 1..31: PE table + h0 ----
        const int xg = (blockIdx.x - 1) * WGS + tid;          // 0..7935
        const int XT = (NWG - 1) * WGS;                        // 7936
        for (int i = xg; i < T_ * 64; i += XT) {
            int t = i >> 6, d = i & 63;
            float div = expf(-(float)(d & ~1) * (9.210340371976184f / 64.0f));  // ln(1e4)/64
            float ang = (float)t * div;
            P.Q[i] = ((d & 1) ? cosf(ang) : sinf(ang)) + P.b_val[d];
        }
        const int xwid = rfl(xg >> 6);                         // 0..123
        const int XW = XT / 64;                                // 124 waves
        float wc[32];
#pragma unroll
        for (int k = 0; k < 32; k++) wc[k] = P.W_sta[k * 64 + lane];
        const float bs = P.b_sta[lane];
        for (int n = xwid; n < N_; n += XW) {
            const float4* nr = (const float4*)(P.nfeat + n * 32);
            float a = bs + P.ada[n * 64 + lane];
#pragma unroll
            for (int q = 0; q < 8; q++) {
                float4 nv = nr[q];
                a = fmaf(nv.x, wc[4 * q + 0], a);
                a = fmaf(nv.y, wc[4 * q + 1], a);
                a = fmaf(nv.z, wc[4 * q + 2], a);
                a = fmaf(nv.w, wc[4 * q + 3], a);
            }
            P.h0[n * 64 + lane] = a;
        }
    }
    grid.sync();  // CSR + h0 visible

    gat_layer<8, 8, false, false>(P.h0, P.h1, P.g0W, P.g0skip, P.g0as, P.g0at, P.g0b,
                                  P.pbuf, P.ss, P.st, P.csrc, P.ofs, grid, gwid, lane);
    gat_layer<8, 8, false, false>(P.h1, P.h2, P.g1W, P.g1skip, P.g1as, P.g1at, P.g1b,
                                  P.pbuf, P.ss, P.st, P.csrc, P.ofs, grid, gwid, lane);
    gat_layer<1, 64, true, true>(P.h2, P.h3, P.g2W, nullptr, P.g2as, P.g2at, P.g2b,
                                 P.pbuf, P.ss, P.st, P.csrc, P.ofs, grid, gwid, lane);
}

// ---------- broadcast: out[b,t,n,d] = x*Wv[d] + Q[t,d] + h3[n,d] ----------
__global__ __launch_bounds__(256) void k_big(const float* __restrict__ x,
                                             const float* __restrict__ Q,
                                             const float* __restrict__ Wv,
                                             const float* __restrict__ h3,
                                             float* __restrict__ out) {
    int row = blockIdx.x * 32 + (threadIdx.x >> 3);  // (b,t,n) linear
    int l8 = threadIdx.x & 7;
    int d0 = l8 * 8;
    int n = row % N_;
    int bt = row / N_;
    int t = bt % T_;
    float xv = x[row];
    float4 q0 = *(const float4*)(Q + t * 64 + d0);
    float4 q1 = *(const float4*)(Q + t * 64 + d0 + 4);
    float4 g0 = *(const float4*)(h3 + n * 64 + d0);
    float4 g1 = *(const float4*)(h3 + n * 64 + d0 + 4);
    float4 w0 = *(const float4*)(Wv + d0);
    float4 w1 = *(const float4*)(Wv + d0 + 4);
    float4 o0, o1;
    o0.x = fmaf(xv, w0.x, q0.x + g0.x);
    o0.y = fmaf(xv, w0.y, q0.y + g0.y);
    o0.z = fmaf(xv, w0.z, q0.z + g0.z);
    o0.w = fmaf(xv, w0.w, q0.w + g0.w);
    o1.x = fmaf(xv, w1.x, q1.x + g1.x);
    o1.y = fmaf(xv, w1.y, q1.y + g1.y);
    o1.z = fmaf(xv, w1.z, q1.z + g1.z);
    o1.w = fmaf(xv, w1.w, q1.w + g1.w);
    float* op = out + row * 64 + d0;
    *(float4*)(op) = o0;
    *(float4*)(op + 4) = o1;
}

extern "C" void kernel_launch(void* const* d_in, const int* in_sizes, int n_in,
                              void* d_out, int out_size, void* d_ws, size_t ws_size,
                              hipStream_t stream) {
    const float* x      = (const float*)d_in[0];
    const float* nfeat  = (const float*)d_in[1];
    const int*   eidx   = (const int*)d_in[2];
    // d_in[3] edge_prob unused (load_trans_prob=False)
    const float* W_val  = (const float*)d_in[4];
    (void)in_sizes; (void)n_in; (void)out_size; (void)ws_size;

    // workspace layout (fp32 + ints), ~508 KB
    float* ws   = (float*)d_ws;
    float* Q    = ws;                  // 288*64
    float* h0   = Q + T_ * 64;         // 307*64 each
    float* h1   = h0 + N_ * 64;
    float* h2   = h1 + N_ * 64;
    float* h3   = h2 + N_ * 64;
    float* pbuf = h3 + N_ * 64;
    float* ssb  = pbuf + N_ * 64;      // 307*8
    float* stb  = ssb + N_ * 8;
    int*   csrc = (int*)(stb + N_ * 8);  // 4912
    int*   ofs  = csrc + E_;             // 308

    Params P;
    P.nfeat = nfeat; P.src = eidx; P.tgt = eidx + E_;
    P.b_val = (const float*)d_in[5];
    P.W_sta = (const float*)d_in[6];
    P.b_sta = (const float*)d_in[7];
    P.ada   = (const float*)d_in[8];
    P.g0W   = (const float*)d_in[9];  P.g0as = (const float*)d_in[10];
    P.g0at  = (const float*)d_in[11]; P.g0b  = (const float*)d_in[12];
    P.g1W   = (const float*)d_in[13]; P.g1as = (const float*)d_in[14];
    P.g1at  = (const float*)d_in[15]; P.g1b  = (const float*)d_in[16];
    P.g2W   = (const float*)d_in[17]; P.g2as = (const float*)d_in[18];
    P.g2at  = (const float*)d_in[19]; P.g2b  = (const float*)d_in[20];
    P.g0skip = (const float*)d_in[21];
    P.g1skip = (const float*)d_in[22];
    P.Q = Q; P.h0 = h0; P.h1 = h1; P.h2 = h2; P.h3 = h3;
    P.pbuf = pbuf; P.ss = ssb; P.st = stb; P.csrc = csrc; P.ofs = ofs;

    // whole GAT in one cooperative dispatch: 32 WGs x 256 thr, 7 grid syncs
    void* kargs[] = { (void*)&P };
    hipLaunchCooperativeKernel((const void*)k_gat, dim3(NWG), dim3(WGS), kargs, 0, stream);

    // broadcast: 707328 rows, 32 rows/block (HBM-write roofline)
    const int ROWS = B_ * T_ * N_;  // 707328
    k_big<<<ROWS / 32, 256, 0, stream>>>(x, Q, W_val, h3, (float*)d_out);
}

// Round 4
// 301.441 us; speedup vs baseline: 3.2516x; 1.3575x over previous
//
#include <hip/hip_runtime.h>
#include <stdint.h>

#define B_ 8
#define T_ 288
#define N_ 307
#define E_ 4912

struct Params {
    const float* nfeat; const int* src; const int* tgt;
    const float* b_val; const float* W_sta; const float* b_sta; const float* ada;
    const float* g0W; const float* g0as; const float* g0at; const float* g0b; const float* g0skip;
    const float* g1W; const float* g1as; const float* g1at; const float* g1b; const float* g1skip;
    const float* g2W; const float* g2as; const float* g2at; const float* g2b;
    float* Q; float* h2; float* h3;
    float* pbuf0; float* ss0; float* st0; float* sk0;
    float* pbuf1; float* ss1; float* st1; float* sk1;
    float* pbuf2; float* ss2; float* st2;
    int* csrc; int* ofs;
};

// ---- softmax-aggregate for node n (exact max, identical order to prior passing kernels) ----
template <int H, int F>
static __device__ __forceinline__ float agg_node(
    int n, int lane, const int* __restrict__ csrc, const int* __restrict__ ofs,
    const float* __restrict__ ss, const float* __restrict__ st,
    const float* __restrict__ pbuf)
{
    const int h = lane / F;        // F=8 -> lane>>3 ; F=64 -> 0
    const int f = lane & (F - 1);
    const int e0 = ofs[n], e1 = ofs[n + 1];
    const float sth = st[n * H + h];
    float m = -1e30f;
    for (int e = e0 + f; e < e1; e += F) {  // strided exact-max pass
        float s = ss[csrc[e] * H + h] + sth;
        s = s > 0.f ? s : 0.2f * s;  // leaky_relu(0.2)
        m = fmaxf(m, s);
    }
#pragma unroll
    for (int o = 1; o < F; o <<= 1) m = fmaxf(m, __shfl_xor(m, o, 64));
    float num = 0.f, den = 0.f;
    for (int e = e0; e < e1; e++) {  // e wave-uniform
        const int s = csrc[e];
        float sc = ss[s * H + h] + sth;
        sc = sc > 0.f ? sc : 0.2f * sc;
        float ev = __expf(sc - m);
        den += ev;
        num = fmaf(ev, pbuf[s * 64 + lane], num);  // coalesced 256B row gather (L2)
    }
    return num / (den + 1e-16f);
}

// ---- row(LDS,64) @ W(64x64) -> per-lane scalar; 4-acc order matches prior kernels ----
static __device__ __forceinline__ float gemm_row(int lane, const float* __restrict__ rb,
                                                 const float* __restrict__ Wg)
{
    float wc[64];
#pragma unroll
    for (int k = 0; k < 64; k++) wc[k] = Wg[k * 64 + lane];
    float a0 = 0.f, a1 = 0.f, a2 = 0.f, a3 = 0.f;
#pragma unroll
    for (int q = 0; q < 16; q++) {
        float4 hv = ((const float4*)rb)[q];
        a0 = fmaf(hv.x, wc[4 * q + 0], a0);
        a1 = fmaf(hv.y, wc[4 * q + 1], a1);
        a2 = fmaf(hv.z, wc[4 * q + 2], a2);
        a3 = fmaf(hv.w, wc[4 * q + 3], a3);
    }
    return (a0 + a1) + (a2 + a3);
}

// ---- projection for node n from its LDS row: pbuf + ss/st ----
template <int H, int F>
static __device__ __forceinline__ void proj_row(
    int n, int lane, const float* __restrict__ rb,
    const float* __restrict__ Wg, const float* __restrict__ asg, const float* __restrict__ atg,
    float* __restrict__ pbuf, float* __restrict__ ss, float* __restrict__ st)
{
    float pd = gemm_row(lane, rb, Wg);
    pbuf[n * 64 + lane] = pd;
    float c0 = pd * asg[lane], c1 = pd * atg[lane];
#pragma unroll
    for (int o = 1; o < F; o <<= 1) {
        c0 += __shfl_xor(c0, o, 64);
        c1 += __shfl_xor(c1, o, 64);
    }
    if ((lane & (F - 1)) == 0) {
        ss[n * H + (lane / F)] = c0;
        st[n * H + (lane / F)] = c1;
    }
}

// ---------- K1: PE + CSR + per-node {h0, proj0, skip0} ----------
__global__ __launch_bounds__(256, 1) void k_prep(Params P) {
    const int tid = threadIdx.x, lane = tid & 63, w = tid >> 6;
    const int bx = blockIdx.x;
    if (bx == 79) {
        // ---- CSR build by tgt (one WG, LDS counting sort) ----
        __shared__ int sA[512], sB[512], scur[512];
        for (int i = tid; i < 512; i += 256) sA[i] = 0;
        __syncthreads();
        for (int e = tid; e < E_; e += 256) atomicAdd(&sA[P.tgt[e]], 1);
        __syncthreads();
        int* in = sA; int* out = sB;
        for (int o = 1; o < 512; o <<= 1) {  // Hillis-Steele inclusive scan
            for (int i = tid; i < 512; i += 256) {
                int v = in[i];
                if (i >= o) v += in[i - o];
                out[i] = v;
            }
            __syncthreads();
            int* t = in; in = out; out = t;
        }
        for (int i = tid; i <= N_; i += 256) P.ofs[i] = (i == 0) ? 0 : in[i - 1];
        for (int i = tid; i < 512; i += 256) scur[i] = 0;
        __syncthreads();
        for (int e = tid; e < E_; e += 256) {
            int t = P.tgt[e];
            int base = (t == 0) ? 0 : in[t - 1];
            int pos = base + atomicAdd(&scur[t], 1);
            P.csrc[pos] = P.src[e];
        }
    } else if (bx >= 77) {
        // ---- PE table: Q[t,d] = pe(t,d) + b_val[d] ----
        for (int i = (bx - 77) * 256 + tid; i < T_ * 64; i += 512) {
            int t = i >> 6, d = i & 63;
            float div = expf(-(float)(d & ~1) * (9.210340371976184f / 64.0f));  // ln(1e4)/64
            float ang = (float)t * div;
            P.Q[i] = ((d & 1) ? cosf(ang) : sinf(ang)) + P.b_val[d];
        }
    } else {
        const int n = bx * 4 + w;  // one wave per node
        if (n < N_) {
            __shared__ float rb[4][64];
            // h0 = nfeat @ W_sta + b_sta + ada   (row n only)
            float wsb[32];
#pragma unroll
            for (int k = 0; k < 32; k++) wsb[k] = P.W_sta[k * 64 + lane];
            float a = P.b_sta[lane] + P.ada[n * 64 + lane];
            const float4* nr = (const float4*)(P.nfeat + n * 32);
#pragma unroll
            for (int q = 0; q < 8; q++) {
                float4 nv = nr[q];
                a = fmaf(nv.x, wsb[4 * q + 0], a);
                a = fmaf(nv.y, wsb[4 * q + 1], a);
                a = fmaf(nv.z, wsb[4 * q + 2], a);
                a = fmaf(nv.w, wsb[4 * q + 3], a);
            }
            rb[w][lane] = a;  // same-wave LDS use: no barrier needed
            proj_row<8, 8>(n, lane, rb[w], P.g0W, P.g0as, P.g0at, P.pbuf0, P.ss0, P.st0);
            P.sk0[n * 64 + lane] = gemm_row(lane, rb[w], P.g0skip);
        }
    }
}

// ---------- K2: agg0 -> h1 (regs) -> proj1 + skip1 ----------
__global__ __launch_bounds__(256, 1) void k_mid0(Params P) {
    const int tid = threadIdx.x, lane = tid & 63, w = tid >> 6;
    const int n = blockIdx.x * 4 + w;
    if (n >= N_) return;
    __shared__ float rb[4][64];
    float outv = agg_node<8, 8>(n, lane, P.csrc, P.ofs, P.ss0, P.st0, P.pbuf0);
    float v = outv + P.sk0[n * 64 + lane] + P.g0b[lane];
    v = v > 0.f ? v : expm1f(v);  // elu
    rb[w][lane] = v;
    proj_row<8, 8>(n, lane, rb[w], P.g1W, P.g1as, P.g1at, P.pbuf1, P.ss1, P.st1);
    P.sk1[n * 64 + lane] = gemm_row(lane, rb[w], P.g1skip);
}

// ---------- K3: agg1 -> h2 (stored for identity skip) -> proj2 ----------
__global__ __launch_bounds__(256, 1) void k_mid1(Params P) {
    const int tid = threadIdx.x, lane = tid & 63, w = tid >> 6;
    const int n = blockIdx.x * 4 + w;
    if (n >= N_) return;
    __shared__ float rb[4][64];
    float outv = agg_node<8, 8>(n, lane, P.csrc, P.ofs, P.ss1, P.st1, P.pbuf1);
    float v = outv + P.sk1[n * 64 + lane] + P.g1b[lane];
    v = v > 0.f ? v : expm1f(v);  // elu
    P.h2[n * 64 + lane] = v;
    rb[w][lane] = v;
    proj_row<1, 64>(n, lane, rb[w], P.g2W, P.g2as, P.g2at, P.pbuf2, P.ss2, P.st2);
}

// ---------- K4: agg2 + identity skip -> h3 (no activation) ----------
__global__ __launch_bounds__(256, 1) void k_fin(Params P) {
    const int tid = threadIdx.x, lane = tid & 63, w = tid >> 6;
    const int n = blockIdx.x * 4 + w;
    if (n >= N_) return;
    float outv = agg_node<1, 64>(n, lane, P.csrc, P.ofs, P.ss2, P.st2, P.pbuf2);
    P.h3[n * 64 + lane] = outv + P.h2[n * 64 + lane] + P.g2b[lane];
}

// ---------- K5: out[b,t,n,d] = x*Wv[d] + Q[t,d] + h3[n,d] ----------
__global__ __launch_bounds__(256) void k_big(const float* __restrict__ x,
                                             const float* __restrict__ Q,
                                             const float* __restrict__ Wv,
                                             const float* __restrict__ h3,
                                             float* __restrict__ out) {
    int row = blockIdx.x * 32 + (threadIdx.x >> 3);  // (b,t,n) linear
    int l8 = threadIdx.x & 7;
    int d0 = l8 * 8;
    int n = row % N_;
    int bt = row / N_;
    int t = bt % T_;
    float xv = x[row];
    float4 q0 = *(const float4*)(Q + t * 64 + d0);
    float4 q1 = *(const float4*)(Q + t * 64 + d0 + 4);
    float4 g0 = *(const float4*)(h3 + n * 64 + d0);
    float4 g1 = *(const float4*)(h3 + n * 64 + d0 + 4);
    float4 w0 = *(const float4*)(Wv + d0);
    float4 w1 = *(const float4*)(Wv + d0 + 4);
    float4 o0, o1;
    o0.x = fmaf(xv, w0.x, q0.x + g0.x);
    o0.y = fmaf(xv, w0.y, q0.y + g0.y);
    o0.z = fmaf(xv, w0.z, q0.z + g0.z);
    o0.w = fmaf(xv, w0.w, q0.w + g0.w);
    o1.x = fmaf(xv, w1.x, q1.x + g1.x);
    o1.y = fmaf(xv, w1.y, q1.y + g1.y);
    o1.z = fmaf(xv, w1.z, q1.z + g1.z);
    o1.w = fmaf(xv, w1.w, q1.w + g1.w);
    float* op = out + row * 64 + d0;
    *(float4*)(op) = o0;
    *(float4*)(op + 4) = o1;
}

extern "C" void kernel_launch(void* const* d_in, const int* in_sizes, int n_in,
                              void* d_out, int out_size, void* d_ws, size_t ws_size,
                              hipStream_t stream) {
    const float* x     = (const float*)d_in[0];
    const float* W_val = (const float*)d_in[4];
    const int*   eidx  = (const int*)d_in[2];
    (void)in_sizes; (void)n_in; (void)out_size; (void)ws_size;

    // workspace layout (fp32 + ints), ~640 KB
    float* ws = (float*)d_ws;
    float* Q     = ws;                 // 288*64
    float* h2    = Q + T_ * 64;        // N*64 each
    float* h3    = h2 + N_ * 64;
    float* pbuf0 = h3 + N_ * 64;
    float* sk0   = pbuf0 + N_ * 64;
    float* pbuf1 = sk0 + N_ * 64;
    float* sk1   = pbuf1 + N_ * 64;
    float* pbuf2 = sk1 + N_ * 64;
    float* ss0   = pbuf2 + N_ * 64;    // N*8 each
    float* st0   = ss0 + N_ * 8;
    float* ss1   = st0 + N_ * 8;
    float* st1   = ss1 + N_ * 8;
    float* ss2   = st1 + N_ * 8;       // N*1 each
    float* st2   = ss2 + N_;
    int*   csrc  = (int*)(st2 + N_);   // E
    int*   ofs   = csrc + E_;          // N+1

    Params P;
    P.nfeat = (const float*)d_in[1];
    P.src = eidx; P.tgt = eidx + E_;
    P.b_val = (const float*)d_in[5];
    P.W_sta = (const float*)d_in[6];
    P.b_sta = (const float*)d_in[7];
    P.ada   = (const float*)d_in[8];
    P.g0W   = (const float*)d_in[9];  P.g0as = (const float*)d_in[10];
    P.g0at  = (const float*)d_in[11]; P.g0b  = (const float*)d_in[12];
    P.g1W   = (const float*)d_in[13]; P.g1as = (const float*)d_in[14];
    P.g1at  = (const float*)d_in[15]; P.g1b  = (const float*)d_in[16];
    P.g2W   = (const float*)d_in[17]; P.g2as = (const float*)d_in[18];
    P.g2at  = (const float*)d_in[19]; P.g2b  = (const float*)d_in[20];
    P.g0skip = (const float*)d_in[21];
    P.g1skip = (const float*)d_in[22];
    P.Q = Q; P.h2 = h2; P.h3 = h3;
    P.pbuf0 = pbuf0; P.ss0 = ss0; P.st0 = st0; P.sk0 = sk0;
    P.pbuf1 = pbuf1; P.ss1 = ss1; P.st1 = st1; P.sk1 = sk1;
    P.pbuf2 = pbuf2; P.ss2 = ss2; P.st2 = st2;
    P.csrc = csrc; P.ofs = ofs;

    // 5 regular (graph-capturable) launches; kernel boundaries = the only barriers
    k_prep<<<80, 256, 0, stream>>>(P);   // PE + CSR + h0/proj0/skip0
    k_mid0<<<77, 256, 0, stream>>>(P);   // agg0 -> proj1/skip1
    k_mid1<<<77, 256, 0, stream>>>(P);   // agg1 -> h2, proj2
    k_fin <<<77, 256, 0, stream>>>(P);   // agg2 -> h3

    const int ROWS = B_ * T_ * N_;  // 707328
    k_big<<<ROWS / 32, 256, 0, stream>>>(x, Q, W_val, h3, (float*)d_out);
}